// Round 1
// 1221.011 us; speedup vs baseline: 1.0030x; 1.0030x over previous
//
#include <hip/hip_runtime.h>
#include <cmath>

// PairNetLayer on MI355X (gfx950). Round 2: fuse the entire edge stage
// (pair build -> norm_gate MLP -> gate -> W_out irrep linear -> +npa) into a
// single per-32-edge-block kernel. All E-scale intermediates (f0e, t1, g,
// gated np1/np2) live in LDS; np1/np2 are recomputed from the L2/L3-resident
// na_* arrays instead of round-tripping HBM; the irrep-interleaved f32 output
// is staged through LDS so every store is a full-line coalesced write.
//
// Sizes: N=4096 nodes, E=65536 edges, MUL=128, TOT=1152, NM=384.

typedef unsigned short u16;
typedef __bf16 v8bf __attribute__((ext_vector_type(8)));
typedef float  v4f  __attribute__((ext_vector_type(4)));

#define NN 4096
#define EE 65536

#define MFMA16 __builtin_amdgcn_mfma_f32_16x16x32_bf16

__device__ __forceinline__ float b2f(u16 u) {
    union { float f; unsigned i; } x; x.i = ((unsigned)u) << 16; return x.f;
}
__device__ __forceinline__ u16 f2b(float f) {  // round-to-nearest-even
    union { float f; unsigned i; } x; x.f = f;
    unsigned i = x.i;
    return (u16)((i + 0x7FFFu + ((i >> 16) & 1u)) >> 16);
}

// ---------------------------------------------------------------------------
// GEMM: C[M,N] = epi(alpha * A[M,K] @ B[K,N] + bias), A bf16 (lda), B given
// pre-transposed bf16: Bt[n*K + k]. M%64==0, N%64==0, K%32==0.
// EPI: 0 = bf16 out; 1 = silu -> bf16 out; 2 = (*mult) -> bf16 out.
// ---------------------------------------------------------------------------
struct GemmP {
    const u16* A; int lda;
    const u16* Bt;
    int M, K, N;
    float alpha;
    const float* bias;   // or null
    u16* outB;
    const u16* mult;     // EPI 2
};

template <int EPI>
__global__ __launch_bounds__(256)
void gemm_k(GemmP p) {
    __shared__ __attribute__((aligned(16))) u16 Al[64][40];
    __shared__ __attribute__((aligned(16))) u16 Bl[64][40];

    const int m0 = blockIdx.x * 64;
    const int n0 = blockIdx.y * 64;
    const int t  = threadIdx.x;
    const int lane = t & 63;
    const int wid  = t >> 6;
    const int wm = (wid & 1) * 32;
    const int wn = (wid >> 1) * 32;
    const int sm = t >> 2;
    const int sk = (t & 3) * 8;
    const int fr = lane & 15;
    const int q  = lane >> 4;

    v4f acc[2][2] = {};

    const u16* Ag = p.A  + (size_t)(m0 + sm) * p.lda + sk;
    const u16* Bg = p.Bt + (size_t)(n0 + sm) * p.K   + sk;

    for (int k0 = 0; k0 < p.K; k0 += 32) {
        uint4 av = *(const uint4*)(Ag + k0);
        uint4 bv = *(const uint4*)(Bg + k0);
        __syncthreads();
        *(uint4*)(&Al[sm][sk]) = av;
        *(uint4*)(&Bl[sm][sk]) = bv;
        __syncthreads();
        v8bf a0 = *(const v8bf*)(&Al[wm +      fr][q * 8]);
        v8bf a1 = *(const v8bf*)(&Al[wm + 16 + fr][q * 8]);
        v8bf b0 = *(const v8bf*)(&Bl[wn +      fr][q * 8]);
        v8bf b1 = *(const v8bf*)(&Bl[wn + 16 + fr][q * 8]);
        acc[0][0] = MFMA16(a0, b0, acc[0][0], 0, 0, 0);
        acc[0][1] = MFMA16(a0, b1, acc[0][1], 0, 0, 0);
        acc[1][0] = MFMA16(a1, b0, acc[1][0], 0, 0, 0);
        acc[1][1] = MFMA16(a1, b1, acc[1][1], 0, 0, 0);
    }

#pragma unroll
    for (int i = 0; i < 2; i++) {
#pragma unroll
        for (int j = 0; j < 2; j++) {
            const int colg = n0 + wn + j * 16 + fr;
            const float bc = p.bias ? p.bias[colg] : 0.0f;
#pragma unroll
            for (int r = 0; r < 4; r++) {
                const int rowg = m0 + wm + i * 16 + q * 4 + r;
                float v = acc[i][j][r] * p.alpha + bc;
                if constexpr (EPI == 0) {
                    p.outB[(size_t)rowg * p.N + colg] = f2b(v);
                } else if constexpr (EPI == 1) {
                    v = v / (1.0f + __expf(-v));
                    p.outB[(size_t)rowg * p.N + colg] = f2b(v);
                } else {
                    v *= b2f(p.mult[(size_t)rowg * p.N + colg]);
                    p.outB[(size_t)rowg * p.N + colg] = f2b(v);
                }
            }
        }
    }
}

// ---------------------------------------------------------------------------
// Weight convert + transpose: dst[n*K+k] = bf16(src[k*N+n])
// ---------------------------------------------------------------------------
struct CvtP { const float* src[15]; u16* dst[15]; int K[15]; int N[15]; };

__global__ void cvt_k(CvtP p) {
    const int j = blockIdx.y;
    const float* s = p.src[j];
    u16* d = p.dst[j];
    const int K = p.K[j], N = p.N[j], tot = K * N;
    for (int idx = blockIdx.x * blockDim.x + threadIdx.x; idx < tot;
         idx += gridDim.x * blockDim.x) {
        const int n = idx / K, k = idx - n * K;
        d[idx] = f2b(s[(size_t)k * N + n]);
    }
}

// ---------------------------------------------------------------------------
// Node-stage prep
// ---------------------------------------------------------------------------
__global__ void node_prep_k(const float* __restrict__ na, u16* __restrict__ x1p,
                            u16* __restrict__ x2p, u16* __restrict__ f0n) {
    const int idx = blockIdx.x * blockDim.x + threadIdx.x;
    if (idx >= NN * 128) return;
    const int n = idx >> 7, u = idx & 127;
    const float* row = na + (size_t)n * 1152;
    f0n[(size_t)n * 384 + u] = f2b(row[u]);
    float s1 = 0.f;
#pragma unroll
    for (int i = 0; i < 3; i++) {
        float v = row[128 + u * 3 + i];
        x1p[((size_t)(n * 3 + i)) * 128 + u] = f2b(v);
        s1 += v * v;
    }
    f0n[(size_t)n * 384 + 128 + u] = f2b(sqrtf(s1));
    float s2 = 0.f;
#pragma unroll
    for (int i = 0; i < 5; i++) {
        float v = row[512 + u * 5 + i];
        x2p[((size_t)(n * 5 + i)) * 128 + u] = f2b(v);
        s2 += v * v;
    }
    f0n[(size_t)n * 384 + 256 + u] = f2b(sqrtf(s2));
}

__global__ void node_gate_k(const float* __restrict__ na, const u16* __restrict__ gn,
                            u16* __restrict__ h1p, u16* __restrict__ h2p) {
    const int idx = blockIdx.x * blockDim.x + threadIdx.x;
    if (idx >= NN * 128) return;
    const int n = idx >> 7, u = idx & 127;
    const float* row = na + (size_t)n * 1152;
    const float g1 = b2f(gn[(size_t)n * 384 + 128 + u]);
#pragma unroll
    for (int i = 0; i < 3; i++)
        h1p[((size_t)(n * 3 + i)) * 128 + u] = f2b(row[128 + u * 3 + i] * g1);
    const float g2 = b2f(gn[(size_t)n * 384 + 256 + u]);
#pragma unroll
    for (int i = 0; i < 5; i++)
        h2p[((size_t)(n * 5 + i)) * 128 + u] = f2b(row[512 + u * 5 + i] * g2);
}

// ---------------------------------------------------------------------------
// we = ssp(edge_attr @ fcE_W1 / 8) @ fcE_W2 / sqrt(8)   (wave per edge)
// ---------------------------------------------------------------------------
__global__ void we_k(const float* __restrict__ ea, const float* __restrict__ W1,
                     const float* __restrict__ W2, u16* __restrict__ we) {
    const int lane = threadIdx.x & 63;
    const int e = blockIdx.x * 4 + (threadIdx.x >> 6);
    const float a = ea[(size_t)e * 64 + lane];
    float t8[8];
#pragma unroll
    for (int h = 0; h < 8; h++) {
        float s = a * W1[lane * 8 + h];
#pragma unroll
        for (int m = 1; m < 64; m <<= 1) s += __shfl_xor(s, m, 64);
        const float x = s * 0.125f;
        const float sp = (x > 20.f) ? x : log1pf(__expf(x));
        t8[h] = sp - 0.6931471805599453f;
    }
    float v0 = 0.f, v1 = 0.f;
#pragma unroll
    for (int h = 0; h < 8; h++) {
        v0 += t8[h] * W2[h * 128 + lane];
        v1 += t8[h] * W2[h * 128 + 64 + lane];
    }
    we[(size_t)e * 128 + lane]      = f2b(v0 * 0.3535533905932738f);
    we[(size_t)e * 128 + 64 + lane] = f2b(v1 * 0.3535533905932738f);
}

// ---------------------------------------------------------------------------
// s0 = [0.5*(p_d0+p_s0) | <p_d1,p_s1>/sqrt3 | <p_d2,p_s2>/sqrt5]  (E x 384)
// ---------------------------------------------------------------------------
__global__ void s0_k(const int* __restrict__ dst, const int* __restrict__ src,
                     const u16* __restrict__ na0_0, const u16* __restrict__ na0_1p,
                     const u16* __restrict__ na0_2p, u16* __restrict__ s0) {
    const int e = blockIdx.x, u = threadIdx.x;
    const int d = dst[e], s = src[e];
    const float v0 = 0.5f * (b2f(na0_0[(size_t)d * 128 + u]) + b2f(na0_0[(size_t)s * 128 + u]));
    float ip1 = 0.f;
#pragma unroll
    for (int i = 0; i < 3; i++)
        ip1 += b2f(na0_1p[((size_t)(d * 3 + i)) * 128 + u]) *
               b2f(na0_1p[((size_t)(s * 3 + i)) * 128 + u]);
    float ip2 = 0.f;
#pragma unroll
    for (int i = 0; i < 5; i++)
        ip2 += b2f(na0_2p[((size_t)(d * 5 + i)) * 128 + u]) *
               b2f(na0_2p[((size_t)(s * 5 + i)) * 128 + u]);
    s0[(size_t)e * 384 + u]       = f2b(v0);
    s0[(size_t)e * 384 + 128 + u] = f2b(ip1 * 0.57735026918962576f);
    s0[(size_t)e * 384 + 256 + u] = f2b(ip2 * 0.44721359549995794f);
}

// ---------------------------------------------------------------------------
// Fused edge stage, 32 edges per 256-thread block (2048 blocks, 2 blocks/CU):
//   P1: F0 = [np0 | ||np1|| | ||np2||]           -> LDS bufA  (np from gathers)
//   P2: T1 = silu(F0 @ ng_W1 + b1)               -> LDS bufN  (B from L2)
//   P3: G  = T1 @ ng_W2 + b2                     -> LDS bufA
//   P4: out[:,0:128]    = G0 @ Wout0*ISQ + bo + npa      (direct, coalesced)
//   P5: np1 rebuilt+gated -> LDS; GEMM Wout1; LDS-transposed coalesced store
//   P6: np2 rebuilt+gated -> LDS; GEMM Wout2; LDS-transposed coalesced store
// LDS: 25088(bufA) + 43520(bufN) + 256(idx) + 8192(wS) = 77056 B -> 2 blk/CU.
// ---------------------------------------------------------------------------
__global__ __launch_bounds__(256, 2)
void edge_fused_k(const int* __restrict__ dst, const int* __restrict__ src,
                  const u16* __restrict__ na_0, const u16* __restrict__ na_1p,
                  const u16* __restrict__ na_2p, const u16* __restrict__ wB,
                  const u16* __restrict__ W1t, const float* __restrict__ b1,
                  const u16* __restrict__ W2t, const float* __restrict__ b2,
                  const u16* __restrict__ Wot, const float* __restrict__ bo,
                  const float* __restrict__ npa, float* __restrict__ out) {
    __shared__ __attribute__((aligned(16))) u16 bufA[32][392];   // F0, then G
    __shared__ __attribute__((aligned(16))) u16 bufN[21760];     // T1 / NP / STG
    __shared__ int dstS[32], srcS[32];
    __shared__ u16 wS[32][128];

    u16 (*T1)[392]   = (u16 (*)[392])bufN;   // [32][392]
    u16 (*NP)[136]   = (u16 (*)[136])bufN;   // [96] or [160] rows
    float (*STG)[68] = (float (*)[68])bufN;  // [96] or [160] rows, 64 cols used

    const int e0 = blockIdx.x * 32;
    const int t = threadIdx.x;
    const int lane = t & 63, wid = t >> 6;
    const int fr = lane & 15, q = lane >> 4;
    const float ISQ = 0.08838834764831845f;  // 1/sqrt(128)

    if (t < 32) { dstS[t] = dst[e0 + t]; srcS[t] = src[e0 + t]; }
#pragma unroll
    for (int rep = 0; rep < 16; rep++) {
        const int idx = rep * 256 + t;
        ((u16*)wS)[idx] = wB[(size_t)e0 * 128 + idx];
    }
    __syncthreads();

    // ---- P1: F0 ----
    for (int rep = 0; rep < 16; rep++) {
        const int idx = rep * 256 + t;
        const int e = idx >> 7, u = idx & 127;
        const int d = dstS[e], s = srcS[e];
        const float v0 = (b2f(na_0[(size_t)d * 128 + u]) + b2f(na_0[(size_t)s * 128 + u]))
                         * b2f(wS[e][u / 9]);
        bufA[e][u] = f2b(v0);
        float n1 = 0.f;
#pragma unroll
        for (int i = 0; i < 3; i++) {
            const float v = (b2f(na_1p[((size_t)(d * 3 + i)) * 128 + u]) +
                             b2f(na_1p[((size_t)(s * 3 + i)) * 128 + u]))
                            * b2f(wS[e][(128 + u * 3 + i) / 9]);
            n1 += v * v;
        }
        bufA[e][128 + u] = f2b(sqrtf(n1));
        float n2 = 0.f;
#pragma unroll
        for (int i = 0; i < 5; i++) {
            const float v = (b2f(na_2p[((size_t)(d * 5 + i)) * 128 + u]) +
                             b2f(na_2p[((size_t)(s * 5 + i)) * 128 + u]))
                            * b2f(wS[e][(512 + u * 5 + i) / 9]);
            n2 += v * v;
        }
        bufA[e][256 + u] = f2b(sqrtf(n2));
    }
    __syncthreads();

    // ---- P2: T1 = silu(F0 @ W1 + b1), M=32 N=384 K=384, wave N-slice 96 ----
    {
        const int wn = wid * 96;
        v4f acc[2][6] = {};
        for (int k0 = 0; k0 < 384; k0 += 32) {
            const v8bf a0 = *(const v8bf*)&bufA[fr][k0 + q * 8];
            const v8bf a1 = *(const v8bf*)&bufA[16 + fr][k0 + q * 8];
#pragma unroll
            for (int j = 0; j < 6; j++) {
                const v8bf b = *(const v8bf*)(W1t + (size_t)(wn + j * 16 + fr) * 384 + k0 + q * 8);
                acc[0][j] = MFMA16(a0, b, acc[0][j], 0, 0, 0);
                acc[1][j] = MFMA16(a1, b, acc[1][j], 0, 0, 0);
            }
        }
#pragma unroll
        for (int i = 0; i < 2; i++)
#pragma unroll
            for (int j = 0; j < 6; j++) {
                const int col = wn + j * 16 + fr;
                const float bb = b1[col];
#pragma unroll
                for (int r = 0; r < 4; r++) {
                    const float v = acc[i][j][r] + bb;
                    T1[i * 16 + q * 4 + r][col] = f2b(v / (1.f + __expf(-v)));
                }
            }
    }
    __syncthreads();

    // ---- P3: G = T1 @ W2 + b2 -> bufA ----
    {
        const int wn = wid * 96;
        v4f acc[2][6] = {};
        for (int k0 = 0; k0 < 384; k0 += 32) {
            const v8bf a0 = *(const v8bf*)&T1[fr][k0 + q * 8];
            const v8bf a1 = *(const v8bf*)&T1[16 + fr][k0 + q * 8];
#pragma unroll
            for (int j = 0; j < 6; j++) {
                const v8bf b = *(const v8bf*)(W2t + (size_t)(wn + j * 16 + fr) * 384 + k0 + q * 8);
                acc[0][j] = MFMA16(a0, b, acc[0][j], 0, 0, 0);
                acc[1][j] = MFMA16(a1, b, acc[1][j], 0, 0, 0);
            }
        }
#pragma unroll
        for (int i = 0; i < 2; i++)
#pragma unroll
            for (int j = 0; j < 6; j++) {
                const int col = wn + j * 16 + fr;
                const float bb = b2[col];
#pragma unroll
                for (int r = 0; r < 4; r++)
                    bufA[i * 16 + q * 4 + r][col] = f2b(acc[i][j][r] + bb);
            }
    }
    __syncthreads();

    // ---- P4: out part0 = G[:,0:128] @ Wout0 * ISQ + bo + npa ----
    {
        const int wn = wid * 32;
        v4f acc[2][2] = {};
        for (int k0 = 0; k0 < 128; k0 += 32) {
            const v8bf a0 = *(const v8bf*)&bufA[fr][k0 + q * 8];
            const v8bf a1 = *(const v8bf*)&bufA[16 + fr][k0 + q * 8];
#pragma unroll
            for (int j = 0; j < 2; j++) {
                const v8bf b = *(const v8bf*)(Wot + (size_t)(wn + j * 16 + fr) * 128 + k0 + q * 8);
                acc[0][j] = MFMA16(a0, b, acc[0][j], 0, 0, 0);
                acc[1][j] = MFMA16(a1, b, acc[1][j], 0, 0, 0);
            }
        }
#pragma unroll
        for (int i = 0; i < 2; i++)
#pragma unroll
            for (int j = 0; j < 2; j++) {
                const int col = wn + j * 16 + fr;
                const float bb = bo[col];
#pragma unroll
                for (int r = 0; r < 4; r++) {
                    const size_t o = (size_t)(e0 + i * 16 + q * 4 + r) * 1152 + col;
                    out[o] = acc[i][j][r] * ISQ + bb + npa[o];
                }
            }
    }

    // ---- P5: part1 — rebuild gated np1 into LDS, GEMM, coalesced store ----
    for (int rep = 0; rep < 48; rep++) {
        const int idx = rep * 256 + t;
        const int row = idx >> 7, u = idx & 127;  // row 0..95
        const int e = row / 3, i = row - e * 3;
        const int d = dstS[e], s = srcS[e];
        const float v = (b2f(na_1p[((size_t)(d * 3 + i)) * 128 + u]) +
                         b2f(na_1p[((size_t)(s * 3 + i)) * 128 + u]))
                        * b2f(wS[e][(128 + u * 3 + i) / 9]);
        NP[row][u] = f2b(v * b2f(bufA[e][128 + u]));
    }
    __syncthreads();
    {
        const int wm = (wid & 1) * 48, wn = (wid >> 1) * 64;
        const u16* Wo1 = Wot + 16384;
        v4f acc[3][4] = {};
        for (int k0 = 0; k0 < 128; k0 += 32) {
            v8bf a[3];
#pragma unroll
            for (int mi = 0; mi < 3; mi++)
                a[mi] = *(const v8bf*)&NP[wm + mi * 16 + fr][k0 + q * 8];
#pragma unroll
            for (int j = 0; j < 4; j++) {
                const v8bf b = *(const v8bf*)(Wo1 + (size_t)(wn + j * 16 + fr) * 128 + k0 + q * 8);
#pragma unroll
                for (int mi = 0; mi < 3; mi++) acc[mi][j] = MFMA16(a[mi], b, acc[mi][j], 0, 0, 0);
            }
        }
        __syncthreads();
        for (int h = 0; h < 2; h++) {
            if ((wid >> 1) == h) {
#pragma unroll
                for (int mi = 0; mi < 3; mi++)
#pragma unroll
                    for (int j = 0; j < 4; j++)
#pragma unroll
                        for (int r = 0; r < 4; r++)
                            STG[wm + mi * 16 + q * 4 + r][j * 16 + fr] = acc[mi][j][r] * ISQ;
            }
            __syncthreads();
            for (int rep = 0; rep < 24; rep++) {
                const int idx = rep * 256 + t;
                const int e = idx / 192, p = idx - e * 192;
                const int c = p / 3, i = p - c * 3;
                const size_t o = (size_t)(e0 + e) * 1152 + 128 + h * 192 + p;
                out[o] = STG[e * 3 + i][c] + npa[o];
            }
            __syncthreads();
        }
    }

    // ---- P6: part2 — rebuild gated np2 into LDS, GEMM, coalesced store ----
    for (int rep = 0; rep < 80; rep++) {
        const int idx = rep * 256 + t;
        const int row = idx >> 7, u = idx & 127;  // row 0..159
        const int e = row / 5, i = row - e * 5;
        const int d = dstS[e], s = srcS[e];
        const float v = (b2f(na_2p[((size_t)(d * 5 + i)) * 128 + u]) +
                         b2f(na_2p[((size_t)(s * 5 + i)) * 128 + u]))
                        * b2f(wS[e][(512 + u * 5 + i) / 9]);
        NP[row][u] = f2b(v * b2f(bufA[e][256 + u]));
    }
    __syncthreads();
    {
        const int wm = (wid & 1) * 80, wn = (wid >> 1) * 64;
        const u16* Wo2 = Wot + 32768;
        v4f acc[5][4] = {};
        for (int k0 = 0; k0 < 128; k0 += 32) {
            v8bf a[5];
#pragma unroll
            for (int mi = 0; mi < 5; mi++)
                a[mi] = *(const v8bf*)&NP[wm + mi * 16 + fr][k0 + q * 8];
#pragma unroll
            for (int j = 0; j < 4; j++) {
                const v8bf b = *(const v8bf*)(Wo2 + (size_t)(wn + j * 16 + fr) * 128 + k0 + q * 8);
#pragma unroll
                for (int mi = 0; mi < 5; mi++) acc[mi][j] = MFMA16(a[mi], b, acc[mi][j], 0, 0, 0);
            }
        }
        __syncthreads();
        for (int h = 0; h < 2; h++) {
            if ((wid >> 1) == h) {
#pragma unroll
                for (int mi = 0; mi < 5; mi++)
#pragma unroll
                    for (int j = 0; j < 4; j++)
#pragma unroll
                        for (int r = 0; r < 4; r++)
                            STG[wm + mi * 16 + q * 4 + r][j * 16 + fr] = acc[mi][j][r] * ISQ;
            }
            __syncthreads();
            for (int rep = 0; rep < 40; rep++) {
                const int idx = rep * 256 + t;
                const int e = idx / 320, p = idx - e * 320;
                const int c = p / 5, i = p - c * 5;
                const size_t o = (size_t)(e0 + e) * 1152 + 512 + h * 320 + p;
                out[o] = STG[e * 5 + i][c] + npa[o];
            }
            __syncthreads();
        }
    }
}

// ---------------------------------------------------------------------------
static inline void launch_gemm(hipStream_t st, int epi, const u16* A, int lda,
                               const u16* Bt, int M, int K, int N, float alpha,
                               const float* bias, u16* outB, const u16* mult) {
    GemmP p{A, lda, Bt, M, K, N, alpha, bias, outB, mult};
    dim3 g(M / 64, N / 64), b(256);
    switch (epi) {
        case 0: gemm_k<0><<<g, b, 0, st>>>(p); break;
        case 1: gemm_k<1><<<g, b, 0, st>>>(p); break;
        case 2: gemm_k<2><<<g, b, 0, st>>>(p); break;
    }
}

extern "C" void kernel_launch(void* const* d_in, const int* in_sizes, int n_in,
                              void* d_out, int out_size, void* d_ws, size_t ws_size,
                              hipStream_t stream) {
    (void)in_sizes; (void)n_in; (void)out_size; (void)ws_size;
    const float* node_attr = (const float*)d_in[0];
    const float* edge_attr = (const float*)d_in[1];
    const int*   dst       = (const int*)d_in[2];
    const int*   src       = (const int*)d_in[3];
    const float* npa       = (const float*)d_in[4];
    const float* W_inner   = (const float*)d_in[5];
    const float* b_inner   = (const float*)d_in[6];
    const float* W_n       = (const float*)d_in[7];
    const float* b_n       = (const float*)d_in[8];
    const float* W_out     = (const float*)d_in[9];
    const float* b_out     = (const float*)d_in[10];
    const float* pre_W1    = (const float*)d_in[11];
    const float* pre_b1    = (const float*)d_in[12];
    const float* pre_W2    = (const float*)d_in[13];
    const float* pre_b2    = (const float*)d_in[14];
    const float* ng_W1     = (const float*)d_in[15];
    const float* ng_b1     = (const float*)d_in[16];
    const float* ng_W2     = (const float*)d_in[17];
    const float* ng_b2     = (const float*)d_in[18];
    const float* fcE_W1    = (const float*)d_in[19];
    const float* fcE_W2    = (const float*)d_in[20];
    const float* fc_W1     = (const float*)d_in[21];
    const float* fc_b1     = (const float*)d_in[22];
    const float* fc_W2     = (const float*)d_in[23];
    const float* fc_b2     = (const float*)d_in[24];
    float* out = (float*)d_out;
    u16* W = (u16*)d_ws;

    // ---- workspace layout (u16 elements) ----
    u16* wbT_inner = W;                  //  3 x 16384
    u16* wbT_n     = W + 49152;
    u16* wbT_out   = W + 98304;
    u16* wbT_pre1  = W + 147456;         //  147456
    u16* wbT_pre2  = W + 294912;
    u16* wbT_ng1   = W + 442368;
    u16* wbT_ng2   = W + 589824;
    u16* wbT_fc1   = W + 737280;         //  49152
    u16* wbT_fc2   = W + 786432;         //  16384
    u16* R1   = W + 802816;              //  shared node-scratch / s0 region
    u16* x1p  = R1;
    u16* x2p  = R1 + 1572864;
    u16* f0n  = R1 + 4194304;
    u16* t1n  = R1 + 5767168;
    u16* gn   = R1 + 7340032;
    u16* hn1p = R1 + 8912896;
    u16* hn2p = R1 + 10485760;
    u16* s0   = R1;                      //  alias: written after node scratch dead
    u16* na0_0  = W + 25968640;
    u16* na0_1p = na0_0 + 524288;
    u16* na0_2p = na0_1p + 1572864;
    u16* na_0   = na0_2p + 2621440;
    u16* na_1p  = na_0 + 524288;
    u16* na_2p  = na_1p + 1572864;
    u16* ws1    = na_2p + 2621440;
    u16* weB    = ws1 + 8388608;
    u16* wB     = weB + 8388608;

    const float ISQ = 0.08838834764831845f;  // 1/sqrt(128)

    // 1. convert + transpose all GEMM weights to bf16 Bt[n*K+k]
    CvtP cp;
    const float* srcs[15] = {W_inner, W_inner + 16384, W_inner + 32768,
                             W_n, W_n + 16384, W_n + 32768,
                             W_out, W_out + 16384, W_out + 32768,
                             pre_W1, pre_W2, ng_W1, ng_W2, fc_W1, fc_W2};
    u16* dsts[15] = {wbT_inner, wbT_inner + 16384, wbT_inner + 32768,
                     wbT_n, wbT_n + 16384, wbT_n + 32768,
                     wbT_out, wbT_out + 16384, wbT_out + 32768,
                     wbT_pre1, wbT_pre2, wbT_ng1, wbT_ng2, wbT_fc1, wbT_fc2};
    const int Ks[15] = {128,128,128,128,128,128,128,128,128,384,384,384,384,384,128};
    const int Ns[15] = {128,128,128,128,128,128,128,128,128,384,384,384,384,128,128};
    for (int j = 0; j < 15; j++) { cp.src[j]=srcs[j]; cp.dst[j]=dsts[j]; cp.K[j]=Ks[j]; cp.N[j]=Ns[j]; }
    cvt_k<<<dim3(64, 15), dim3(256), 0, stream>>>(cp);

    // 2. node prep (f0n, x1p, x2p)
    node_prep_k<<<dim3(2048), dim3(256), 0, stream>>>(node_attr, x1p, x2p, f0n);

    // 3-5. na0 = irrep_linear(node_attr, W_inner, b_inner)
    launch_gemm(stream, 0, f0n, 384, wbT_inner,          4096, 128, 128, ISQ, b_inner, na0_0, 0);
    launch_gemm(stream, 0, x1p, 128, wbT_inner + 16384, 12288, 128, 128, ISQ, nullptr, na0_1p, 0);
    launch_gemm(stream, 0, x2p, 128, wbT_inner + 32768, 20480, 128, 128, ISQ, nullptr, na0_2p, 0);

    // 6-8. node norm_gate (pre)
    launch_gemm(stream, 1, f0n, 384, wbT_pre1, 4096, 384, 384, 1.f, pre_b1, t1n, 0);
    launch_gemm(stream, 0, t1n, 384, wbT_pre2, 4096, 384, 384, 1.f, pre_b2, gn, 0);
    node_gate_k<<<dim3(2048), dim3(256), 0, stream>>>(node_attr, gn, hn1p, hn2p);

    // 9-11. na = irrep_linear(gated, W_n, b_n)
    launch_gemm(stream, 0, gn,   384, wbT_n,          4096, 128, 128, ISQ, b_n,     na_0,  0);
    launch_gemm(stream, 0, hn1p, 128, wbT_n + 16384, 12288, 128, 128, ISQ, nullptr, na_1p, 0);
    launch_gemm(stream, 0, hn2p, 128, wbT_n + 32768, 20480, 128, 128, ISQ, nullptr, na_2p, 0);

    // 12. we (edge MLP on edge_attr)
    we_k<<<dim3(EE / 4), dim3(256), 0, stream>>>(edge_attr, fcE_W1, fcE_W2, weB);

    // 13. s0 from na0 gathers
    s0_k<<<dim3(EE), dim3(128), 0, stream>>>(dst, src, na0_0, na0_1p, na0_2p, s0);

    // 14-15. ws = silu(s0@fc_W1+b1)@fc_W2+b2 ; w = ws * we
    launch_gemm(stream, 1, s0,  384, wbT_fc1, EE, 384, 128, 1.f, fc_b1, ws1, 0);
    launch_gemm(stream, 2, ws1, 128, wbT_fc2, EE, 128, 128, 1.f, fc_b2, wB,  weB);

    // 16. fused edge stage: pair build + norm_gate + gate + W_out irrep + npa
    edge_fused_k<<<dim3(EE / 32), dim3(256), 0, stream>>>(
        dst, src, na_0, na_1p, na_2p, wB,
        wbT_ng1, ng_b1, wbT_ng2, ng_b2, wbT_out, b_out, npa, out);
}